// Round 5
// baseline (498.175 us; speedup 1.0000x reference)
//
#include <hip/hip_runtime.h>
#include <math.h>

// ---- problem constants ----
#define NM 50000
#define ND 10000
#define NA 25000
#define E_DM 150000
#define E_AM 300000
#define E_TOT (E_DM + E_AM)
#define HID 256
#define HEADS 8
#define HD 32
#define FIN 1024
#define SCALE 0.17677669529663687f  // 1/sqrt(32)

typedef __attribute__((ext_vector_type(8))) short short8;
typedef __attribute__((ext_vector_type(4))) float f32x4;

typedef __attribute__((address_space(1))) const unsigned char gas_u8;
typedef __attribute__((address_space(3))) unsigned char las_u8;

// async global->LDS 16B: global per-lane address, LDS wave-uniform base (+lane*16 by HW)
__device__ __forceinline__ void gload16(const void* g, void* l) {
    gas_u8* gp = (gas_u8*)(unsigned long long)(uintptr_t)g;
    las_u8* lp = (las_u8*)(unsigned int)(uintptr_t)l;
    __builtin_amdgcn_global_load_lds((const __attribute__((address_space(1))) void*)gp,
                                     (__attribute__((address_space(3))) void*)lp, 16, 0, 0);
}

// RNE f32 -> bf16
__device__ __forceinline__ unsigned int pk_bf16(float x, float y) {
    unsigned int a = __float_as_uint(x), b = __float_as_uint(y);
    a += 0x7FFFu + ((a >> 16) & 1u);
    b += 0x7FFFu + ((b >> 16) & 1u);
    return (a >> 16) | (b & 0xFFFF0000u);
}
__device__ __forceinline__ unsigned short to_bf16(float x) {
    unsigned int a = __float_as_uint(x);
    a += 0x7FFFu + ((a >> 16) & 1u);
    return (unsigned short)(a >> 16);
}

// ---- fold per-head relation matrix into W (4 descs in one launch) ----
struct F4 { const float* W[4]; const float* b[4]; const float* a[4]; float* Wf[4]; float* bf[4]; };
__global__ void fold_w4(F4 f4) {
    int di = blockIdx.y;
    const float* W = f4.W[di]; const float* b = f4.b[di]; const float* a = f4.a[di];
    float* Wf = f4.Wf[di]; float* bf = f4.bf[di];
    int c = threadIdx.x;
    int h = c >> 5, f = c & 31;
    int r = blockIdx.x;
    float acc = 0.f;
    if (r < HID) {
        #pragma unroll
        for (int d = 0; d < HD; ++d)
            acc += W[r * HID + h * HD + d] * a[(h * HD + d) * HD + f];
        Wf[r * HID + c] = acc;
    } else {
        #pragma unroll
        for (int d = 0; d < HD; ++d)
            acc += b[h * HD + d] * a[(h * HD + d) * HD + f];
        bf[c] = acc;
    }
}

// ---- pack W fp32 [K][256] -> bf16 fragment order [K/32][16 subtile][64 lane][8] ----
struct PDesc { const float* W; unsigned short* out; int K; int b0; };
struct PMulti { PDesc d[9]; int nd; };
__global__ void wt_pack(PMulti pm) {
    int bid = blockIdx.x; int di = 0;
    #pragma unroll
    for (int i = 1; i < 9; ++i) if (i < pm.nd && bid >= pm.d[i].b0) di = i;
    PDesc p = pm.d[di];
    int kstep = bid - p.b0;
    int t = threadIdx.x;
    #pragma unroll
    for (int i = 0; i < 32; ++i) {
        int idx = i * 256 + t;
        int n0 = idx >> 9, r = idx & 511, lane = r >> 3, j = r & 7;
        int k = kstep * 32 + (lane >> 4) * 8 + j;
        int c = n0 * 16 + (lane & 15);
        p.out[(size_t)kstep * 8192 + idx] = to_bf16(p.W[(size_t)k * HID + c]);
    }
}

// ---- multi-descriptor MFMA GEMM: C[M,256] = A[M,K]@B + bias ----
// A-fragments live in registers (wave owns 16 rows, 2-step prefetch);
// B double-buffered in LDS via global_load_lds with counted vmcnt + raw barriers.
struct GDesc {
    const float* A; const unsigned short* Bt; const float* bias; float* C;
    const float* hskip; const float* gate; int M; int K; int epi; int obf; int b0;
};
struct GMulti { GDesc d[5]; int nd; };

#define GBM 64

__launch_bounds__(256)
__global__ void gemm_mfma(GMulti mu) {
    __shared__ unsigned short sB[2][16 * 512];   // 32 KB

    int bid = blockIdx.x;
    int di = 0;
    #pragma unroll
    for (int i = 1; i < 5; ++i)
        if (i < mu.nd && bid >= mu.d[i].b0) di = i;
    GDesc g = mu.d[di];
    int bm = (bid - g.b0) * GBM;
    int M = g.M, K = g.K;
    int nk = K >> 5;

    int t = threadIdx.x;
    int lane = t & 63;
    int w = t >> 6;                  // 0..3 (wave id)

    int row = bm + w * 16 + (lane & 15);
    int rcl = min(row, M - 1);
    const float* Ap = g.A + (size_t)rcl * K + ((lane >> 4) * 8);

    // prologue (FIFO shape must be [A(0), B(0), A(1)] = steady-state invariant)
    float4 s0a = *(const float4*)(Ap + 0);
    float4 s0b = *(const float4*)(Ap + 4);
    {
        const unsigned short* gB = g.Bt;
        #pragma unroll
        for (int i = 0; i < 4; ++i)
            gload16(gB + (w * 4 + i) * 512 + lane * 8, &sB[0][(w * 4 + i) * 512]);
    }
    int ka1 = (nk > 1 ? 32 : 0);
    float4 s1a = *(const float4*)(Ap + ka1);
    float4 s1b = *(const float4*)(Ap + ka1 + 4);

    f32x4 acc[16];
    #pragma unroll
    for (int n = 0; n < 16; ++n) acc[n] = (f32x4)(0.f);

    for (int ks = 0; ks < nk; ++ks) {
        if (ks > 0) __builtin_amdgcn_s_barrier();   // protect sB[(ks+1)&1] WAR
        // pack A(ks) -> bf16 fragment (compiler inserts the vmcnt for A(ks))
        union { short8 s; uint4 u; } Af;
        if ((ks & 1) == 0)
            Af.u = make_uint4(pk_bf16(s0a.x, s0a.y), pk_bf16(s0a.z, s0a.w),
                              pk_bf16(s0b.x, s0b.y), pk_bf16(s0b.z, s0b.w));
        else
            Af.u = make_uint4(pk_bf16(s1a.x, s1a.y), pk_bf16(s1a.z, s1a.w),
                              pk_bf16(s1b.x, s1b.y), pk_bf16(s1b.z, s1b.w));
        // issue B(ks+1) into the other buffer (clamped at tail; never read then)
        {
            int kb = min(ks + 1, nk - 1);
            const unsigned short* gB = g.Bt + (size_t)kb * 8192;
            #pragma unroll
            for (int i = 0; i < 4; ++i)
                gload16(gB + (w * 4 + i) * 512 + lane * 8, &sB[(ks + 1) & 1][(w * 4 + i) * 512]);
        }
        // issue A(ks+2) into the slot freed by the pack above
        {
            int ka = min(ks + 2, nk - 1) * 32;
            if ((ks & 1) == 0) { s0a = *(const float4*)(Ap + ka); s0b = *(const float4*)(Ap + ka + 4); }
            else               { s1a = *(const float4*)(Ap + ka); s1b = *(const float4*)(Ap + ka + 4); }
        }
        // counted wait: completes B(ks) (4 ops) while leaving B(ks+1)+A(ks+1)+A(ks+2)=8 in flight
        asm volatile("s_waitcnt vmcnt(8)" ::: "memory");
        __builtin_amdgcn_sched_barrier(0);
        __builtin_amdgcn_s_barrier();               // all waves' B(ks) visible in LDS
        const unsigned short* sBc = &sB[ks & 1][0];
        #pragma unroll
        for (int n = 0; n < 16; ++n) {
            short8 bfr = *(const short8*)&sBc[n * 512 + lane * 8];
            acc[n] = __builtin_amdgcn_mfma_f32_16x16x32_bf16(Af.s, bfr, acc[n], 0, 0, 0);
        }
    }

    float beta = 0.f;
    if (g.epi) beta = 1.f / (1.f + expf(-g.gate[0]));
    int r0 = bm + w * 16 + ((lane >> 4) << 2);
    #pragma unroll
    for (int n = 0; n < 16; ++n) {
        int col = n * 16 + (lane & 15);
        #pragma unroll
        for (int j = 0; j < 4; ++j) {
            int grow = r0 + j;
            if (grow >= M) continue;
            float v = acc[n][j] + g.bias[col];
            if (g.epi) {
                float x = v;
                float gl = 0.5f * x * (1.f + tanhf(0.7978845608028654f * (x + 0.044715f * x * x * x)));
                v = beta * gl + (1.f - beta) * g.hskip[(size_t)grow * HID + col];
            }
            if (g.obf) ((unsigned short*)g.C)[(size_t)grow * HID + col] = to_bf16(v);
            else g.C[(size_t)grow * HID + col] = v;
        }
    }
}

// ---- CSR build ----
__global__ void hist_deg(const int* __restrict__ dA, const int* __restrict__ dB,
                         int* __restrict__ deg) {
    int i = blockIdx.x * 256 + threadIdx.x;
    if (i < E_DM) atomicAdd(&deg[dA[i]], 1);
    else if (i < E_TOT) atomicAdd(&deg[dB[i - E_DM]], 1);
}

__global__ void scan_pass1(const int* __restrict__ deg, int* __restrict__ bsum) {
    __shared__ int s[256];
    int b = blockIdx.x, t = threadIdx.x;
    int i = b * 256 + t;
    int v = (i < NM) ? deg[i] : 0;
    s[t] = v; __syncthreads();
    for (int off = 128; off > 0; off >>= 1) {
        if (t < off) s[t] += s[t + off];
        __syncthreads();
    }
    if (t == 0) bsum[b] = s[0];
}

__global__ void scan_pass2(const int* __restrict__ bsum, int* __restrict__ boff, int nb) {
    __shared__ int s[256];
    int t = threadIdx.x;
    int v = (t < nb) ? bsum[t] : 0;
    s[t] = v; __syncthreads();
    for (int off = 1; off < 256; off <<= 1) {
        int x = (t >= off) ? s[t - off] : 0;
        __syncthreads();
        s[t] += x;
        __syncthreads();
    }
    if (t < nb) boff[t] = s[t] - v;   // exclusive
}

__global__ void scan_pass3(const int* __restrict__ deg, const int* __restrict__ boff,
                           int* __restrict__ rowptr, int* __restrict__ cursor) {
    __shared__ int s[256];
    int b = blockIdx.x, t = threadIdx.x, i = b * 256 + t;
    int v = (i < NM) ? deg[i] : 0;
    s[t] = v; __syncthreads();
    for (int off = 1; off < 256; off <<= 1) {
        int x = (t >= off) ? s[t - off] : 0;
        __syncthreads();
        s[t] += x;
        __syncthreads();
    }
    int excl = s[t] - v + boff[b];
    if (i < NM) { rowptr[i] = excl; cursor[i] = excl; }
    if (i == 0) rowptr[NM] = E_TOT;
}

__global__ void fill_adj(const int* __restrict__ sA, const int* __restrict__ dA,
                         const int* __restrict__ sB, const int* __restrict__ dB,
                         int* __restrict__ cursor, int* __restrict__ adj) {
    int i = blockIdx.x * 256 + threadIdx.x;
    int d, entry;
    if (i < E_DM)      { d = dA[i];        entry = sA[i]; }
    else if (i < E_TOT){ int j = i - E_DM; d = dB[j]; entry = (sB[j] + ND) | (1 << 16); }
    else return;
    int pos = atomicAdd(&cursor[d], 1);
    adj[pos] = entry;
}

// ---- fused per-destination attention aggregation: one wave per node ----
__launch_bounds__(256)
__global__ void agg_fused(const int* __restrict__ rowptr, const int* __restrict__ adj,
                          const float* __restrict__ q, const unsigned short* __restrict__ kt_all,
                          const unsigned short* __restrict__ vt_all,
                          const float* __restrict__ p_dm, const float* __restrict__ p_am,
                          float* __restrict__ agg) {
    int d = blockIdx.x * 4 + (threadIdx.x >> 6);
    if (d >= NM) return;
    int lane = threadIdx.x & 63;
    int h = lane >> 3;                       // 8 lanes per head, 4 dims per lane
    int start = rowptr[d], end = rowptr[d + 1];
    float4 qv = *(const float4*)(q + (size_t)d * HID + lane * 4);
    float pr0 = p_dm[h] * SCALE, pr1 = p_am[h] * SCALE;
    float m = -INFINITY, den = 0.f, a0 = 0.f, a1 = 0.f, a2 = 0.f, a3 = 0.f;
    for (int i = start; i < end; ++i) {
        int e = adj[i];
        int sr = e & 0xFFFF;
        uint2 ku = *(const uint2*)(kt_all + (size_t)sr * HID + lane * 4);
        float k0 = __uint_as_float(ku.x << 16), k1 = __uint_as_float(ku.x & 0xFFFF0000u);
        float k2 = __uint_as_float(ku.y << 16), k3 = __uint_as_float(ku.y & 0xFFFF0000u);
        float prod = qv.x * k0 + qv.y * k1 + qv.z * k2 + qv.w * k3;
        prod += __shfl_xor(prod, 1);
        prod += __shfl_xor(prod, 2);
        prod += __shfl_xor(prod, 4);
        float a = prod * ((e >> 16) ? pr1 : pr0);
        float mn = fmaxf(m, a);
        float c  = __expf(m - mn);
        float ex = __expf(a - mn);
        uint2 vu = *(const uint2*)(vt_all + (size_t)sr * HID + lane * 4);
        float v0 = __uint_as_float(vu.x << 16), v1 = __uint_as_float(vu.x & 0xFFFF0000u);
        float v2 = __uint_as_float(vu.y << 16), v3 = __uint_as_float(vu.y & 0xFFFF0000u);
        den = den * c + ex;
        a0 = a0 * c + ex * v0; a1 = a1 * c + ex * v1;
        a2 = a2 * c + ex * v2; a3 = a3 * c + ex * v3;
        m = mn;
    }
    float inv = (end > start) ? 1.f / den : 0.f;
    *(float4*)(agg + (size_t)d * HID + lane * 4) = make_float4(a0 * inv, a1 * inv, a2 * inv, a3 * inv);
}

// out[M,4] = X[M,256] @ W[256,4] + b
__launch_bounds__(256)
__global__ void classifier(const float* __restrict__ X, const float* __restrict__ W,
                           const float* __restrict__ b, float* __restrict__ out, int M) {
    int t = threadIdx.x, lane = t & 63;
    int wid = blockIdx.x * 4 + (t >> 6);
    int nw = gridDim.x * 4;
    float w0[4], w1[4], w2[4], w3[4];
    #pragma unroll
    for (int j = 0; j < 4; ++j) {
        float4 wv = *(const float4*)(W + (lane * 4 + j) * 4);
        w0[j] = wv.x; w1[j] = wv.y; w2[j] = wv.z; w3[j] = wv.w;
    }
    float b0 = b[0], b1 = b[1], b2 = b[2], b3 = b[3];
    for (int row = wid; row < M; row += nw) {
        float4 x = *(const float4*)(X + (size_t)row * HID + lane * 4);
        float s0 = x.x * w0[0] + x.y * w0[1] + x.z * w0[2] + x.w * w0[3];
        float s1 = x.x * w1[0] + x.y * w1[1] + x.z * w1[2] + x.w * w1[3];
        float s2 = x.x * w2[0] + x.y * w2[1] + x.z * w2[2] + x.w * w2[3];
        float s3 = x.x * w3[0] + x.y * w3[1] + x.z * w3[2] + x.w * w3[3];
        #pragma unroll
        for (int off = 32; off > 0; off >>= 1) {
            s0 += __shfl_xor(s0, off); s1 += __shfl_xor(s1, off);
            s2 += __shfl_xor(s2, off); s3 += __shfl_xor(s3, off);
        }
        if (lane == 0) {
            float4 o = make_float4(s0 + b0, s1 + b1, s2 + b2, s3 + b3);
            *(float4*)(out + (size_t)row * 4) = o;
        }
    }
}

extern "C" void kernel_launch(void* const* d_in, const int* in_sizes, int n_in,
                              void* d_out, int out_size, void* d_ws, size_t ws_size,
                              hipStream_t stream) {
    (void)in_sizes; (void)n_in; (void)out_size; (void)ws_size;
    const float* x_movie    = (const float*)d_in[0];
    const float* x_director = (const float*)d_in[1];
    const float* x_actor    = (const float*)d_in[2];
    const int*   e_dm_src = (const int*)d_in[8];
    const int*   e_dm_dst = (const int*)d_in[9];
    const float* a_dm     = (const float*)d_in[10];
    const float* m_dm     = (const float*)d_in[11];
    const float* p_dm     = (const float*)d_in[12];
    const int*   e_am_src = (const int*)d_in[18];
    const int*   e_am_dst = (const int*)d_in[19];
    const float* a_am     = (const float*)d_in[20];
    const float* m_am     = (const float*)d_in[21];
    const float* p_am     = (const float*)d_in[22];
    const float* W_in_m = (const float*)d_in[23];
    const float* b_in_m = (const float*)d_in[24];
    const float* Wq_m   = (const float*)d_in[27];
    const float* bq_m   = (const float*)d_in[28];
    const float* Wa_m   = (const float*)d_in[31];
    const float* ba_m   = (const float*)d_in[32];
    const float* skip_m = (const float*)d_in[33];
    const float* W_in_d = (const float*)d_in[34];
    const float* b_in_d = (const float*)d_in[35];
    const float* Wk_d   = (const float*)d_in[36];
    const float* bk_d   = (const float*)d_in[37];
    const float* Wv_d   = (const float*)d_in[40];
    const float* bv_d   = (const float*)d_in[41];
    const float* W_in_a = (const float*)d_in[45];
    const float* b_in_a = (const float*)d_in[46];
    const float* Wk_a   = (const float*)d_in[47];
    const float* bk_a   = (const float*)d_in[48];
    const float* Wv_a   = (const float*)d_in[51];
    const float* bv_a   = (const float*)d_in[52];
    const float* W_out  = (const float*)d_in[56];
    const float* b_out  = (const float*)d_in[57];

    // ---- workspace layout (byte cursor, 256B aligned) ----
    char* base = (char*)d_ws;
    size_t off = 0;
    auto alloc = [&](size_t bytes) -> void* {
        void* p = base + off;
        off = (off + bytes + 255) & ~(size_t)255;
        return p;
    };
    float* h_m    = (float*)alloc((size_t)NM * HID * 4);
    float* h_d    = (float*)alloc((size_t)ND * HID * 4);
    float* h_a    = (float*)alloc((size_t)NA * HID * 4);
    float* q_m    = (float*)alloc((size_t)NM * HID * 4);   // reused as out_movie
    float* agg    = (float*)alloc((size_t)NM * HID * 4);
    unsigned short* kt_all = (unsigned short*)alloc((size_t)(ND + NA) * HID * 2);
    unsigned short* vt_all = (unsigned short*)alloc((size_t)(ND + NA) * HID * 2);
    float* Wf     = (float*)alloc(4 * (size_t)HID * HID * 4);
    float* bf     = (float*)alloc(4 * (size_t)HID * 4);
    int* deg      = (int*)alloc(NM * 4);
    int* rowptr   = (int*)alloc((NM + 1) * 4);
    int* cursor   = (int*)alloc(NM * 4);
    int* bsum     = (int*)alloc(256 * 4);
    int* boff     = (int*)alloc(256 * 4);
    int* adj      = (int*)alloc((size_t)E_TOT * 4);
    unsigned short* Bt_in_m = (unsigned short*)alloc((size_t)256 * 1024 * 2);
    unsigned short* Bt_in_d = (unsigned short*)alloc((size_t)256 * 1024 * 2);
    unsigned short* Bt_in_a = (unsigned short*)alloc((size_t)256 * 1024 * 2);
    unsigned short* Bt_q_m  = (unsigned short*)alloc((size_t)256 * 256 * 2);
    unsigned short* Bt_k_dm = (unsigned short*)alloc((size_t)256 * 256 * 2);
    unsigned short* Bt_v_dm = (unsigned short*)alloc((size_t)256 * 256 * 2);
    unsigned short* Bt_k_am = (unsigned short*)alloc((size_t)256 * 256 * 2);
    unsigned short* Bt_v_am = (unsigned short*)alloc((size_t)256 * 256 * 2);
    unsigned short* Bt_a_m  = (unsigned short*)alloc((size_t)256 * 256 * 2);

    unsigned short* kt_dm = kt_all;
    unsigned short* kt_am = kt_all + (size_t)ND * HID;
    unsigned short* vt_dm = vt_all;
    unsigned short* vt_am = vt_all + (size_t)ND * HID;

    float* Wf_k_dm = Wf + 0 * HID * HID;  float* bf_k_dm = bf + 0 * HID;
    float* Wf_v_dm = Wf + 1 * HID * HID;  float* bf_v_dm = bf + 1 * HID;
    float* Wf_k_am = Wf + 2 * HID * HID;  float* bf_k_am = bf + 2 * HID;
    float* Wf_v_am = Wf + 3 * HID * HID;  float* bf_v_am = bf + 3 * HID;

    // ---- CSR build ----
    hipMemsetAsync(deg, 0, NM * sizeof(int), stream);
    hist_deg<<<(E_TOT + 255) / 256, 256, 0, stream>>>(e_dm_dst, e_am_dst, deg);
    int nb = (NM + 255) / 256;  // 196
    scan_pass1<<<nb, 256, 0, stream>>>(deg, bsum);
    scan_pass2<<<1, 256, 0, stream>>>(bsum, boff, nb);
    scan_pass3<<<nb, 256, 0, stream>>>(deg, boff, rowptr, cursor);
    fill_adj<<<(E_TOT + 255) / 256, 256, 0, stream>>>(e_dm_src, e_dm_dst, e_am_src, e_am_dst,
                                                      cursor, adj);

    // ---- fold relation matrices (1 launch) ----
    {
        F4 f4{};
        f4.W[0] = Wk_d; f4.b[0] = bk_d; f4.a[0] = a_dm; f4.Wf[0] = Wf_k_dm; f4.bf[0] = bf_k_dm;
        f4.W[1] = Wv_d; f4.b[1] = bv_d; f4.a[1] = m_dm; f4.Wf[1] = Wf_v_dm; f4.bf[1] = bf_v_dm;
        f4.W[2] = Wk_a; f4.b[2] = bk_a; f4.a[2] = a_am; f4.Wf[2] = Wf_k_am; f4.bf[2] = bf_k_am;
        f4.W[3] = Wv_a; f4.b[3] = bv_a; f4.a[3] = m_am; f4.Wf[3] = Wf_v_am; f4.bf[3] = bf_v_am;
        fold_w4<<<dim3(257, 4), 256, 0, stream>>>(f4);
    }
    // ---- pack all B matrices to fragment order (1 launch) ----
    {
        PMulti pm{};
        pm.nd = 9;
        int b0 = 0;
        pm.d[0] = {W_in_m,  Bt_in_m, FIN, b0}; b0 += 32;
        pm.d[1] = {W_in_d,  Bt_in_d, FIN, b0}; b0 += 32;
        pm.d[2] = {W_in_a,  Bt_in_a, FIN, b0}; b0 += 32;
        pm.d[3] = {Wq_m,    Bt_q_m,  HID, b0}; b0 += 8;
        pm.d[4] = {Wf_k_dm, Bt_k_dm, HID, b0}; b0 += 8;
        pm.d[5] = {Wf_v_dm, Bt_v_dm, HID, b0}; b0 += 8;
        pm.d[6] = {Wf_k_am, Bt_k_am, HID, b0}; b0 += 8;
        pm.d[7] = {Wf_v_am, Bt_v_am, HID, b0}; b0 += 8;
        pm.d[8] = {Wa_m,    Bt_a_m,  HID, b0}; b0 += 8;
        wt_pack<<<b0, 256, 0, stream>>>(pm);
    }

    int bm_m = (NM + GBM - 1) / GBM;  // 782
    int bm_d = (ND + GBM - 1) / GBM;  // 157
    int bm_a = (NA + GBM - 1) / GBM;  // 391

    // launch (a): input projections, K=1024
    {
        GMulti mu{};
        mu.nd = 3;
        mu.d[0] = {x_movie,    Bt_in_m, b_in_m, h_m, nullptr, nullptr, NM, FIN, 0, 0, 0};
        mu.d[1] = {x_director, Bt_in_d, b_in_d, h_d, nullptr, nullptr, ND, FIN, 0, 0, bm_m};
        mu.d[2] = {x_actor,    Bt_in_a, b_in_a, h_a, nullptr, nullptr, NA, FIN, 0, 0, bm_m + bm_d};
        gemm_mfma<<<bm_m + bm_d + bm_a, 256, 0, stream>>>(mu);
    }
    // launch (b): q/k/v projections, K=256 (kt/vt output bf16)
    {
        GMulti mu{};
        mu.nd = 5;
        int b0 = 0;
        mu.d[0] = {h_m, Bt_q_m,  bq_m,    q_m,            nullptr, nullptr, NM, HID, 0, 0, b0}; b0 += bm_m;
        mu.d[1] = {h_d, Bt_k_dm, bf_k_dm, (float*)kt_dm,  nullptr, nullptr, ND, HID, 0, 1, b0}; b0 += bm_d;
        mu.d[2] = {h_d, Bt_v_dm, bf_v_dm, (float*)vt_dm,  nullptr, nullptr, ND, HID, 0, 1, b0}; b0 += bm_d;
        mu.d[3] = {h_a, Bt_k_am, bf_k_am, (float*)kt_am,  nullptr, nullptr, NA, HID, 0, 1, b0}; b0 += bm_a;
        mu.d[4] = {h_a, Bt_v_am, bf_v_am, (float*)vt_am,  nullptr, nullptr, NA, HID, 0, 1, b0}; b0 += bm_a;
        gemm_mfma<<<b0, 256, 0, stream>>>(mu);
    }

    // fused per-destination aggregation
    agg_fused<<<(NM + 3) / 4, 256, 0, stream>>>(rowptr, adj, q_m, kt_all, vt_all, p_dm, p_am, agg);

    // launch (c): out_movie = beta*gelu(agg@Wa+ba)+(1-beta)*h_m  (into q_m)
    {
        GMulti mu{};
        mu.nd = 1;
        mu.d[0] = {agg, Bt_a_m, ba_m, q_m, h_m, skip_m, NM, HID, 1, 0, 0};
        gemm_mfma<<<bm_m, 256, 0, stream>>>(mu);
    }

    // classifier
    classifier<<<256, 256, 0, stream>>>(q_m, W_out, b_out, (float*)d_out, NM);
}